// Round 8
// baseline (212.245 us; speedup 1.0000x reference)
//
#include <hip/hip_runtime.h>
#include <hip/hip_bf16.h>

#define BB 8
#define CC 128
#define NN 512
#define TT 12
#define HH 4
#define C4 32

typedef float f32x4 __attribute__((ext_vector_type(4)));
typedef __bf16 bf16x8 __attribute__((ext_vector_type(8)));
typedef __bf16 bf16x4 __attribute__((ext_vector_type(4)));

// ---------------- kernel A0: transpose W1,W2 into Wt[c][o] (uniform/scalar-load friendly)
__global__ __launch_bounds__(256) void wtrans_k(const float* __restrict__ W1,
                                                const float* __restrict__ W2,
                                                float* __restrict__ Wt) {
    int idx = blockIdx.x * 256 + threadIdx.x;   // 0..32767
    int sel = idx >> 14;                        // 0: W1, 1: W2
    int r   = idx & 16383;
    int o = r >> 7, c = r & 127;
    const float* W = sel ? W2 : W1;
    Wt[sel * 16384 + c * 128 + o] = W[r];
}

// ---------------- kernel A: fused 1x1 convs (fp32 exact), store bf16 [slice][h][n][c4]
// No LDS: per-lane seq element via global_load (vmcnt, in-order, pipelinable) —
// keeps SMEM weight waits (lgkmcnt) decoupled from the data path. Both convs
// fused: one seq load feeds 32 FMAs. o-space split 8x16 -> grid 1536 = 6
// blocks/CU = 24 waves/CU so per-iter SMEM drain is TLP-covered.
__global__ __launch_bounds__(256) void conv_k(const float* __restrict__ seq,
                                              const float* __restrict__ Wt,
                                              __hip_bfloat16* __restrict__ F1,
                                              __hip_bfloat16* __restrict__ F2) {
    int bid = blockIdx.x;               // 1536 = 8 xcd * (2 o-half * 96 slices)
    int xcd = bid & 7;
    int g   = bid >> 3;                 // 0..191
    int oh  = g & 1;                    // which o-half this block covers
    int gg  = g >> 1;                   // 0..95
    int t   = gg % TT;
    int b   = gg / TT;
    int n0  = xcd * 64;                 // n-tile pinned per XCD: t-siblings share seq lines
    int slice = b * TT + t;

    int tid = threadIdx.x;
    int n   = tid & 63;                                         // lane id == n offset
    int og16 = __builtin_amdgcn_readfirstlane(oh * 4 + (tid >> 6)); // wave-uniform, 0..7

    const float* W1v = Wt + og16 * 16;            // + c*128, 64B-aligned -> s_load_dwordx16
    const float* W2v = Wt + 16384 + og16 * 16;
    const float* sp  = seq + ((size_t)b * CC * NN + (size_t)(n0 + n)) * TT + t;  // + c*NN*TT

    float acc1[16], acc2[16];
#pragma unroll
    for (int m = 0; m < 16; ++m) { acc1[m] = 0.0f; acc2[m] = 0.0f; }

#pragma unroll 2
    for (int c = 0; c < CC; ++c) {
        float s = sp[(size_t)c * NN * TT];        // per-lane global load (vmcnt)
#pragma unroll
        for (int m = 0; m < 16; ++m) {
            acc1[m] = fmaf(W1v[c * 128 + m], s, acc1[m]);   // uniform s_load weights
            acc2[m] = fmaf(W2v[c * 128 + m], s, acc2[m]);
        }
    }

    // o = og16*16 + m, m = j*4 + h  ->  h = o&3, c4 = og16*4 + j (j contiguous -> 8B store)
#pragma unroll
    for (int h = 0; h < 4; ++h) {
        bf16x4 v1, v2;
#pragma unroll
        for (int j = 0; j < 4; ++j) {
            v1[j] = (__bf16)acc1[j * 4 + h];
            v2[j] = (__bf16)acc2[j * 4 + h];
        }
        size_t off = ((size_t)(slice * HH + h) * NN + (n0 + n)) * C4 + og16 * 4;
        *(bf16x4*)&F1[off] = v1;
        *(bf16x4*)&F2[off] = v2;
    }
}

// ---------------- kernel B: logits via MFMA (K=32 per head) + sigmoid-mean
__global__ __launch_bounds__(256) void att_k(const __hip_bfloat16* __restrict__ F1,
                                             const __hip_bfloat16* __restrict__ F2,
                                             float* __restrict__ out) {
    int bid = blockIdx.x;                 // 6144 = 8 xcd * 64 tiles * 12
    int xcd = bid & 7, g = bid >> 3;      // keep all 64 tiles of a slice on one XCD
    int tile = g & 63, sg = g >> 6;       // sg 0..11
    int slice = sg * 8 + xcd;             // 0..95
    int ti = tile >> 3, tj = tile & 7;
    int n0 = ti * 64, q0 = tj * 64;

    int tid = threadIdx.x;
    int w = tid >> 6, l = tid & 63;
    int wr = w >> 1, wc = w & 1;          // 4 waves in 2x2 of 32x32
    int nw = n0 + wr * 32, qw = q0 + wc * 32;
    int lr = l & 15, lg = l >> 4;

    const __hip_bfloat16* F1s = F1 + (size_t)slice * HH * NN * C4;
    const __hip_bfloat16* F2s = F2 + (size_t)slice * HH * NN * C4;

    f32x4 oacc[2][2];
#pragma unroll
    for (int i = 0; i < 2; ++i)
#pragma unroll
        for (int j = 0; j < 2; ++j) oacc[i][j] = (f32x4){0.f, 0.f, 0.f, 0.f};

#pragma unroll
    for (int h = 0; h < HH; ++h) {
        const __hip_bfloat16* f1h = F1s + h * NN * C4;
        const __hip_bfloat16* f2h = F2s + h * NN * C4;
        // A frag: row = nw+lr (output n), k-slots 8*lg..+7 (contiguous c4, 16B load)
        bf16x8 a0 = *(const bf16x8*)(f1h + (nw + lr) * C4 + 8 * lg);
        bf16x8 a1 = *(const bf16x8*)(f1h + (nw + 16 + lr) * C4 + 8 * lg);
        // B frag: col = qw+lr (output q), same k-slot mapping (A/B mirror symmetry
        // means any consistent slot->k bijection cancels between operands)
        bf16x8 b0 = *(const bf16x8*)(f2h + (qw + lr) * C4 + 8 * lg);
        bf16x8 b1 = *(const bf16x8*)(f2h + (qw + 16 + lr) * C4 + 8 * lg);
        f32x4 z = {0.f, 0.f, 0.f, 0.f};
        f32x4 l00 = __builtin_amdgcn_mfma_f32_16x16x32_bf16(a0, b0, z, 0, 0, 0);
        f32x4 l01 = __builtin_amdgcn_mfma_f32_16x16x32_bf16(a0, b1, z, 0, 0, 0);
        f32x4 l10 = __builtin_amdgcn_mfma_f32_16x16x32_bf16(a1, b0, z, 0, 0, 0);
        f32x4 l11 = __builtin_amdgcn_mfma_f32_16x16x32_bf16(a1, b1, z, 0, 0, 0);
#pragma unroll
        for (int r = 0; r < 4; ++r) {
            oacc[0][0][r] += __builtin_amdgcn_rcpf(1.0f + __expf(-l00[r]));
            oacc[0][1][r] += __builtin_amdgcn_rcpf(1.0f + __expf(-l01[r]));
            oacc[1][0][r] += __builtin_amdgcn_rcpf(1.0f + __expf(-l10[r]));
            oacc[1][1][r] += __builtin_amdgcn_rcpf(1.0f + __expf(-l11[r]));
        }
    }

    // C/D layout (m89-verified): col = lane&15, row = 4*(lane>>4) + reg
    float* outs = out + (size_t)slice * NN * NN;
#pragma unroll
    for (int i = 0; i < 2; ++i) {
#pragma unroll
        for (int j = 0; j < 2; ++j) {
#pragma unroll
            for (int r = 0; r < 4; ++r) {
                int nn = nw + i * 16 + 4 * lg + r;
                int q  = qw + j * 16 + lr;
                outs[nn * NN + q] = 0.25f * oacc[i][j][r];
            }
        }
    }
}

extern "C" void kernel_launch(void* const* d_in, const int* in_sizes, int n_in,
                              void* d_out, int out_size, void* d_ws, size_t ws_size,
                              hipStream_t stream) {
    const float* seq = (const float*)d_in[0];
    const float* W1  = (const float*)d_in[1];
    const float* W2  = (const float*)d_in[2];
    float* out = (float*)d_out;

    // ws layout: [Wt: 2*16384 f32 = 128KB][F1: 12.58MB bf16][F2: 12.58MB bf16]
    float* Wt = (float*)d_ws;
    __hip_bfloat16* F1 = (__hip_bfloat16*)((char*)d_ws + 2 * 16384 * sizeof(float));
    __hip_bfloat16* F2 = F1 + (size_t)96 * HH * NN * C4;

    wtrans_k<<<128, 256, 0, stream>>>(W1, W2, Wt);
    conv_k<<<1536, 256, 0, stream>>>(seq, Wt, F1, F2);
    att_k<<<6144, 256, 0, stream>>>(F1, F2, out);
}

// Round 12
// 187.718 us; speedup vs baseline: 1.1307x; 1.1307x over previous
//
#include <hip/hip_runtime.h>
#include <hip/hip_bf16.h>

#define BB 8
#define CC 128
#define NN 512
#define TT 12
#define HH 4
#define C4 32

typedef float f32x4 __attribute__((ext_vector_type(4)));
typedef __bf16 bf16x8 __attribute__((ext_vector_type(8)));
typedef __bf16 bf16x4 __attribute__((ext_vector_type(4)));

// ---------------- kernel A0: transpose W1,W2 into Wt[c][o] (uniform/scalar-load friendly)
__global__ __launch_bounds__(256) void wtrans_k(const float* __restrict__ W1,
                                                const float* __restrict__ W2,
                                                float* __restrict__ Wt) {
    int idx = blockIdx.x * 256 + threadIdx.x;   // 0..32767
    int sel = idx >> 14;                        // 0: W1, 1: W2
    int r   = idx & 16383;
    int o = r >> 7, c = r & 127;
    const float* W = sel ? W2 : W1;
    Wt[sel * 16384 + c * 128 + o] = W[r];
}

// ---------------- kernel A: fused 1x1 convs (fp32 exact), store bf16 [slice][h][n][c4]
// Coalescing fix (r8 post-mortem): lane = consecutive (n,t) pair, so the per-c
// seq wave-load covers 256B contiguous = 4 cache lines (was 48 with lane=n,
// stride 48B). Weights on the uniform s_load path. 16 o's per wave per conv.
__global__ __launch_bounds__(256) void conv_k(const float* __restrict__ seq,
                                              const float* __restrict__ Wt,
                                              __hip_bfloat16* __restrict__ F1,
                                              __hip_bfloat16* __restrict__ F2) {
    int bid = blockIdx.x;               // 1536 = (96 ntc * 2 oh) * 8 b
    int b   = bid & 7;                  // xcd = b: og-siblings share L2 for write-merge
    int r   = bid >> 3;
    int oh  = r & 1;                    // o-half
    int ntc = r >> 1;                   // 0..95: which 64-pair chunk of the (n,t) plane

    int tid = threadIdx.x;
    int lnt = tid & 63;                                             // lane nt offset
    int og16 = __builtin_amdgcn_readfirstlane(oh * 4 + (tid >> 6)); // wave-uniform 0..7

    int p = ntc * 64 + lnt;             // flat (n,t): p = n*12 + t
    int n = p / TT, t = p % TT;
    int slice = b * TT + t;

    const float* W1v = Wt + og16 * 16;            // + c*128 -> s_load_dwordx16
    const float* W2v = Wt + 16384 + og16 * 16;
    const float* sp  = seq + (size_t)b * CC * NN * TT + p;   // + c*NN*TT, coalesced

    float acc1[16], acc2[16];
#pragma unroll
    for (int m = 0; m < 16; ++m) { acc1[m] = 0.0f; acc2[m] = 0.0f; }

#pragma unroll 2
    for (int c = 0; c < CC; ++c) {
        float s = sp[(size_t)c * NN * TT];        // per-lane global load, 4 lines/wave
#pragma unroll
        for (int m = 0; m < 16; ++m) {
            acc1[m] = fmaf(W1v[c * 128 + m], s, acc1[m]);   // uniform s_load weights
            acc2[m] = fmaf(W2v[c * 128 + m], s, acc2[m]);
        }
    }

    // o = og16*16 + m, m = j*4 + h  ->  h = o&3, c4 = og16*4 + j (8B store; the 8
    // og16 sibling waves/blocks complete each 64B F line, merged in same-XCD L2)
#pragma unroll
    for (int h = 0; h < 4; ++h) {
        bf16x4 v1, v2;
#pragma unroll
        for (int j = 0; j < 4; ++j) {
            v1[j] = (__bf16)acc1[j * 4 + h];
            v2[j] = (__bf16)acc2[j * 4 + h];
        }
        size_t off = ((size_t)(slice * HH + h) * NN + n) * C4 + og16 * 4;
        *(bf16x4*)&F1[off] = v1;
        *(bf16x4*)&F2[off] = v2;
    }
}

// ---------------- kernel B: logits via MFMA (K=32 per head) + sigmoid-mean
__global__ __launch_bounds__(256) void att_k(const __hip_bfloat16* __restrict__ F1,
                                             const __hip_bfloat16* __restrict__ F2,
                                             float* __restrict__ out) {
    int bid = blockIdx.x;                 // 6144 = 8 xcd * 64 tiles * 12
    int xcd = bid & 7, g = bid >> 3;      // keep all 64 tiles of a slice on one XCD
    int tile = g & 63, sg = g >> 6;       // sg 0..11
    int slice = sg * 8 + xcd;             // 0..95
    int ti = tile >> 3, tj = tile & 7;
    int n0 = ti * 64, q0 = tj * 64;

    int tid = threadIdx.x;
    int w = tid >> 6, l = tid & 63;
    int wr = w >> 1, wc = w & 1;          // 4 waves in 2x2 of 32x32
    int nw = n0 + wr * 32, qw = q0 + wc * 32;
    int lr = l & 15, lg = l >> 4;

    const __hip_bfloat16* F1s = F1 + (size_t)slice * HH * NN * C4;
    const __hip_bfloat16* F2s = F2 + (size_t)slice * HH * NN * C4;

    f32x4 oacc[2][2];
#pragma unroll
    for (int i = 0; i < 2; ++i)
#pragma unroll
        for (int j = 0; j < 2; ++j) oacc[i][j] = (f32x4){0.f, 0.f, 0.f, 0.f};

#pragma unroll
    for (int h = 0; h < HH; ++h) {
        const __hip_bfloat16* f1h = F1s + h * NN * C4;
        const __hip_bfloat16* f2h = F2s + h * NN * C4;
        // A frag: row = nw+lr (output n), k-slots 8*lg..+7 (contiguous c4, 16B load)
        bf16x8 a0 = *(const bf16x8*)(f1h + (nw + lr) * C4 + 8 * lg);
        bf16x8 a1 = *(const bf16x8*)(f1h + (nw + 16 + lr) * C4 + 8 * lg);
        // B frag: col = qw+lr (output q), same k-slot mapping (A/B mirror symmetry
        // means any consistent slot->k bijection cancels between operands)
        bf16x8 b0 = *(const bf16x8*)(f2h + (qw + lr) * C4 + 8 * lg);
        bf16x8 b1 = *(const bf16x8*)(f2h + (qw + 16 + lr) * C4 + 8 * lg);
        f32x4 z = {0.f, 0.f, 0.f, 0.f};
        f32x4 l00 = __builtin_amdgcn_mfma_f32_16x16x32_bf16(a0, b0, z, 0, 0, 0);
        f32x4 l01 = __builtin_amdgcn_mfma_f32_16x16x32_bf16(a0, b1, z, 0, 0, 0);
        f32x4 l10 = __builtin_amdgcn_mfma_f32_16x16x32_bf16(a1, b0, z, 0, 0, 0);
        f32x4 l11 = __builtin_amdgcn_mfma_f32_16x16x32_bf16(a1, b1, z, 0, 0, 0);
#pragma unroll
        for (int r = 0; r < 4; ++r) {
            oacc[0][0][r] += __builtin_amdgcn_rcpf(1.0f + __expf(-l00[r]));
            oacc[0][1][r] += __builtin_amdgcn_rcpf(1.0f + __expf(-l01[r]));
            oacc[1][0][r] += __builtin_amdgcn_rcpf(1.0f + __expf(-l10[r]));
            oacc[1][1][r] += __builtin_amdgcn_rcpf(1.0f + __expf(-l11[r]));
        }
    }

    // C/D layout (m89-verified): col = lane&15, row = 4*(lane>>4) + reg
    float* outs = out + (size_t)slice * NN * NN;
#pragma unroll
    for (int i = 0; i < 2; ++i) {
#pragma unroll
        for (int j = 0; j < 2; ++j) {
#pragma unroll
            for (int r = 0; r < 4; ++r) {
                int nn = nw + i * 16 + 4 * lg + r;
                int q  = qw + j * 16 + lr;
                outs[nn * NN + q] = 0.25f * oacc[i][j][r];
            }
        }
    }
}

extern "C" void kernel_launch(void* const* d_in, const int* in_sizes, int n_in,
                              void* d_out, int out_size, void* d_ws, size_t ws_size,
                              hipStream_t stream) {
    const float* seq = (const float*)d_in[0];
    const float* W1  = (const float*)d_in[1];
    const float* W2  = (const float*)d_in[2];
    float* out = (float*)d_out;

    // ws layout: [Wt: 2*16384 f32 = 128KB][F1: 12.58MB bf16][F2: 12.58MB bf16]
    float* Wt = (float*)d_ws;
    __hip_bfloat16* F1 = (__hip_bfloat16*)((char*)d_ws + 2 * 16384 * sizeof(float));
    __hip_bfloat16* F2 = F1 + (size_t)96 * HH * NN * C4;

    wtrans_k<<<128, 256, 0, stream>>>(W1, W2, Wt);
    conv_k<<<1536, 256, 0, stream>>>(seq, Wt, F1, F2);
    att_k<<<6144, 256, 0, stream>>>(F1, F2, out);
}